// Round 5
// baseline (159.359 us; speedup 1.0000x reference)
//
#include <hip/hip_runtime.h>
#include <hip/hip_bf16.h>

#define NE 8192
#define BATCH 64
#define NNZT (NE * 32)
#define KSPLIT 8
#define KCH (NE / KSPLIT)  // 1024 k per wave
#define BK 32              // k per step
#define NSTEP (KCH / BK)   // 32 steps
#define SLOTB 6144         // ring slot bytes per wave (2 KB W + 4 KB x)
#define WAVEB 12288        // 2 slots per wave

typedef float f32x4 __attribute__((ext_vector_type(4)));
typedef short s16x8 __attribute__((ext_vector_type(8)));

__device__ __forceinline__ unsigned short f2bf(float f) {
  unsigned u = __builtin_bit_cast(unsigned, f);
  return (unsigned short)((u + 0x7FFFu + ((u >> 16) & 1u)) >> 16);  // RNE
}

__device__ __forceinline__ s16x8 cvt8(f32x4 a, f32x4 b) {
  s16x8 r;
#pragma unroll
  for (int j = 0; j < 4; ++j) {
    r[j] = (short)f2bf(a[j]);
    r[j + 4] = (short)f2bf(b[j]);
  }
  return r;
}

__device__ __forceinline__ void gld16(const void* g, void* l) {
  __builtin_amdgcn_global_load_lds(
      (const __attribute__((address_space(1))) unsigned int*)g,
      (__attribute__((address_space(3))) unsigned int*)l, 16, 0, 0);
}

__device__ __forceinline__ unsigned lds_off(const void* p) {
  return (unsigned)(uintptr_t)(const __attribute__((address_space(3))) char*)p;
}

// x fp32 [64][8192] -> bf16 (as ushort)
__global__ void k_convert_x(const float* __restrict__ x, unsigned short* __restrict__ xb) {
  int i = (blockIdx.x * 256 + threadIdx.x) * 4;
  float4 v = *reinterpret_cast<const float4*>(x + i);
  *reinterpret_cast<ushort4*>(xb + i) =
      make_ushort4(f2bf(v.x), f2bf(v.y), f2bf(v.z), f2bf(v.w));
}

__global__ void k_zero(float* __restrict__ p) {
  int i = (blockIdx.x * 256 + threadIdx.x) * 4;
  *reinterpret_cast<float4*>(p + i) = make_float4(0.f, 0.f, 0.f, 0.f);
}

// h = x @ W^T stored transposed ht[i][b], partial-K via atomicAdd.
// Barrier-free per-wave private DMA ring: each wave owns 16 W rows x 1024 k,
// stages W (2 gld16) + all 64 x rows (4 gld16) per BK=32 step into its own
// 2-slot LDS ring. ALL LDS reads are inline-asm ds_read_b128 so the compiler
// cannot inject vmcnt(0) drains; the only waits are counted vmcnt + lgkmcnt.
// Chunk-XOR swizzle (pos = chunk ^ ((row>>1)&3)) applied on pre-swizzled
// global source + asm read address -> 2-way LDS conflicts (free).
__global__ __launch_bounds__(256, 3) void k_dense(const unsigned short* __restrict__ xb,
                                                  const float* __restrict__ W,
                                                  float* __restrict__ ht) {
  __shared__ __align__(16) char smem[4 * WAVEB];  // 48 KB: 4 waves x 2 slots x 6 KB
  const int tid = threadIdx.x;
  const int wave = tid >> 6, l = tid & 63;
  const int kq = blockIdx.x & (KSPLIT - 1);
  const int i0 = (blockIdx.x >> 3) * 64;
  const int k0 = kq * KCH;

  char* const wbase = smem + wave * WAVEB;  // generic ptr for DMA dests (wave-uniform)

  // ---- staging source addresses (per lane) ----
  const int sr = l >> 2, sc = l & 3;          // staging row (0..15), slot pos
  const int schunk = sc ^ ((sr >> 1) & 3);    // swizzled source chunk
  const float* wsrc = W + (size_t)(i0 + wave * 16 + sr) * NE + k0 + schunk * 4;
  const unsigned short* xsrc = xb + (size_t)sr * NE + k0 + schunk * 8;

  // ---- fragment read addresses (asm ds_read, slot via offset imm) ----
  const int r = l & 15, q = l >> 4;
  const int fr = (r >> 1) & 3;
  const unsigned base0 = lds_off(wbase);
  const unsigned wA0 = base0 + (q >> 1) * 1024 + r * 64 + ((((q & 1) * 2 + 0) ^ fr) * 16);
  const unsigned wA1 = base0 + (q >> 1) * 1024 + r * 64 + ((((q & 1) * 2 + 1) ^ fr) * 16);
  const unsigned xA0 = base0 + 2048 + r * 64 + ((q ^ fr) * 16);

  f32x4 acc[4] = {};

#define STAGE(s, SLOT)                                         \
  do {                                                         \
    const float* w_ = wsrc + (size_t)(s)*BK;                   \
    gld16(w_, wbase + (SLOT));                                 \
    gld16(w_ + 16, wbase + (SLOT) + 1024);                     \
    const unsigned short* x_ = xsrc + (size_t)(s)*BK;          \
    gld16(x_, wbase + (SLOT) + 2048);                          \
    gld16(x_ + (size_t)16 * NE, wbase + (SLOT) + 3072);        \
    gld16(x_ + (size_t)32 * NE, wbase + (SLOT) + 4096);        \
    gld16(x_ + (size_t)48 * NE, wbase + (SLOT) + 5120);        \
  } while (0)

#define DSR(dst, addr, OFS)                                    \
  asm volatile("ds_read_b128 %0, %1 offset:" #OFS              \
               : "=v"(dst) : "v"(addr))

#define ITER(s, OFS, WAITN, DO_STAGE)                          \
  do {                                                         \
    asm volatile("s_waitcnt vmcnt(" #WAITN ")" ::: "memory");  \
    __builtin_amdgcn_sched_barrier(0);                         \
    f32x4 w0_, w1_;                                            \
    s16x8 a0_, a1_, a2_, a3_;                                  \
    DSR(w0_, wA0, OFS);                                        \
    DSR(w1_, wA1, OFS);                                        \
    DSR(a0_, xA0, OFS);                                        \
    DSR(a1_, xA0, OFS + 1024);                                 \
    DSR(a2_, xA0, OFS + 2048);                                 \
    DSR(a3_, xA0, OFS + 3072);                                 \
    asm volatile("s_waitcnt lgkmcnt(0)" ::: "memory");         \
    __builtin_amdgcn_sched_barrier(0);                         \
    if (DO_STAGE) STAGE((s) + 2, OFS);                         \
    s16x8 bfr_ = cvt8(w0_, w1_);                               \
    acc[0] = __builtin_amdgcn_mfma_f32_16x16x32_bf16(a0_, bfr_, acc[0], 0, 0, 0); \
    acc[1] = __builtin_amdgcn_mfma_f32_16x16x32_bf16(a1_, bfr_, acc[1], 0, 0, 0); \
    acc[2] = __builtin_amdgcn_mfma_f32_16x16x32_bf16(a2_, bfr_, acc[2], 0, 0, 0); \
    acc[3] = __builtin_amdgcn_mfma_f32_16x16x32_bf16(a3_, bfr_, acc[3], 0, 0, 0); \
  } while (0)

  STAGE(0, 0);
  STAGE(1, SLOTB);

  for (int s2 = 0; s2 < NSTEP - 2; s2 += 2) {
    ITER(s2, 0, 6, true);
    ITER(s2 + 1, 6144, 6, true);
  }
  ITER(NSTEP - 2, 0, 6, false);
  ITER(NSTEP - 1, 6144, 0, false);

#undef ITER
#undef DSR
#undef STAGE

  // C/D: i = i0 + wave*16 + r (col = lane&15), b = g*16 + q*4 + j
  float* hp = ht + (size_t)(i0 + wave * 16 + r) * BATCH + q * 4;
#pragma unroll
  for (int g = 0; g < 4; ++g)
#pragma unroll
    for (int j = 0; j < 4; ++j)
      atomicAdd(hp + g * 16 + j, acc[g][j]);
}

// out_t[c][b] += ht[r][b] * w  for each nnz. One wave per nnz-chunk, lane = b.
__global__ void k_scatter(const float* __restrict__ ht, const float* __restrict__ sw,
                          const int* __restrict__ rows, const int* __restrict__ cols,
                          float* __restrict__ out_t) {
  const int w = (blockIdx.x * 256 + threadIdx.x) >> 6;  // 0..4095
  const int lane = threadIdx.x & 63;
  const int n0 = w * (NNZT / 4096);                     // 64 nnz per wave
#pragma unroll 4
  for (int n = n0; n < n0 + (NNZT / 4096); ++n) {
    const int r = rows[n];
    const int c = cols[n];
    const float wv = sw[n];
    atomicAdd(out_t + (size_t)c * BATCH + lane, ht[(size_t)r * BATCH + lane] * wv);
  }
}

// out[b][j] = leaky(out_t[j][b]) via LDS transpose. Grid 128 (j-tiles of 64).
__global__ void k_final(const float* __restrict__ out_t, float* __restrict__ out) {
  __shared__ float tile[64][65];
  const int t = threadIdx.x;
  const int j0 = blockIdx.x * 64;
  {
    const int jl = t >> 2, b0 = (t & 3) * 16;
    const float* src = out_t + (size_t)(j0 + jl) * BATCH + b0;
#pragma unroll
    for (int e = 0; e < 16; e += 4) {
      float4 v = *reinterpret_cast<const float4*>(src + e);
      tile[jl][b0 + e + 0] = v.x;
      tile[jl][b0 + e + 1] = v.y;
      tile[jl][b0 + e + 2] = v.z;
      tile[jl][b0 + e + 3] = v.w;
    }
  }
  __syncthreads();
  {
    const int bl = t >> 2, js = (t & 3) * 16;
    float* dst = out + (size_t)bl * NE + j0 + js;
#pragma unroll
    for (int e = 0; e < 16; e += 4) {
      float a0 = tile[js + e + 0][bl];
      float a1 = tile[js + e + 1][bl];
      float a2 = tile[js + e + 2][bl];
      float a3 = tile[js + e + 3][bl];
      float4 v;
      v.x = a0 >= 0.f ? a0 : 0.001f * a0;
      v.y = a1 >= 0.f ? a1 : 0.001f * a1;
      v.z = a2 >= 0.f ? a2 : 0.001f * a2;
      v.w = a3 >= 0.f ? a3 : 0.001f * a3;
      *reinterpret_cast<float4*>(dst + e) = v;
    }
  }
}

extern "C" void kernel_launch(void* const* d_in, const int* in_sizes, int n_in,
                              void* d_out, int out_size, void* d_ws, size_t ws_size,
                              hipStream_t stream) {
  const float* x = (const float*)d_in[0];
  const float* W = (const float*)d_in[1];
  const float* sw = (const float*)d_in[2];
  const int* idx = (const int*)d_in[3];  // [2][NNZ]: rows then cols
  float* out = (float*)d_out;

  char* ws = (char*)d_ws;
  float* ht = (float*)ws;                                   // 2 MB: ht[8192][64]
  float* out_t = (float*)(ws + (2 << 20));                  // 2 MB: out_t[8192][64]
  unsigned short* xbf = (unsigned short*)(ws + (4 << 20));  // 1 MB: x in bf16

  k_convert_x<<<512, 256, 0, stream>>>(x, xbf);
  k_zero<<<1024, 256, 0, stream>>>((float*)ws);  // zero ht + out_t (4 MB)
  k_dense<<<1024, 256, 0, stream>>>(xbf, W, ht);
  k_scatter<<<1024, 256, 0, stream>>>(ht, sw, idx, idx + NNZT, out_t);
  k_final<<<128, 256, 0, stream>>>(out_t, out);
}